// Round 4
// baseline (123.935 us; speedup 1.0000x reference)
//
#include <hip/hip_runtime.h>

// DCNv2 forward = prep (weight repack + NHWC fp16 transpose) + FUSED
// im2col+GEMM. R16: wave-private barrier-free main loop on the R15 fp16
// skeleton. Each wave owns 16 px x ALL 64 cout; its B-tile (16px x 64ch
// fp16, double-buffered) lives in a wave-private LDS region -> no cross-
// wave dependency -> ZERO __syncthreads in the 9-tap loop (one barrier
// total, after coefs). Loads stay in flight across taps (counted vmcnt,
// no barrier drain); 16 independent waves/CU hide gather latency.
// Pipeline unchanged: ISSUE(t+2)->LA/LB regs, MFMA(t)<-Bt[t&1],
// FINISH(t+1)->Bt[t&1^1].
#define N_    4
#define C_    64
#define H_    128
#define W_    128
#define KW_   3
#define K_    9
#define COUT_ 64
#define HW_   (H_ * W_)     // 16384
#define NPIX  (N_ * HW_)    // 65536
#define KK_   (C_ * K_)     // 576

typedef _Float16 h4 __attribute__((ext_vector_type(4)));
typedef _Float16 h8 __attribute__((ext_vector_type(8)));   // 16B, 4 VGPRs
typedef float v4f __attribute__((ext_vector_type(4)));     // MFMA C/D
typedef int   v4i __attribute__((ext_vector_type(4)));

// ---------------------------------------------------------------------------
// prep: one dispatch doing both prologue jobs.
//   blocks 0..1023  : NCHW fp32 -> NHWC fp16 transpose xh[n][hw][c]
//   blocks 1024..1167: wA3[o][k] = fp16(weight[o][c][tap]), k = tap*64+c
// ---------------------------------------------------------------------------
__global__ __launch_bounds__(256) void prep(
    const float* __restrict__ x, _Float16* __restrict__ xh,
    const float* __restrict__ w, _Float16* __restrict__ wA3)
{
    if (blockIdx.x < 1024) {
        const int n   = blockIdx.x >> 8;            // 4 images x 256 hw-tiles
        const int hw0 = (blockIdx.x & 255) * 64;

        __shared__ float tile[64][65];              // [hw][c], pad
        const float* xb = x + n * (C_ * HW_);
#pragma unroll
        for (int i = 0; i < 4; ++i) {
            const int idx = i * 256 + threadIdx.x;  // 0..1023
            const int q   = idx & 15;               // hw quad 0..15
            const int c   = idx >> 4;               // 0..63
            const v4f v = *(const v4f*)&xb[c * HW_ + hw0 + 4 * q];
            tile[4 * q + 0][c] = v.x;
            tile[4 * q + 1][c] = v.y;
            tile[4 * q + 2][c] = v.z;
            tile[4 * q + 3][c] = v.w;
        }
        __syncthreads();
        _Float16* xo = xh + ((size_t)n * HW_ + hw0) * 64;
#pragma unroll
        for (int i = 0; i < 4; ++i) {
            const int idx = i * 256 + threadIdx.x;
            const int c4  = idx & 15;               // c quad 0..15
            const int hr  = idx >> 4;               // 0..63
            h4 v;
            v.x = (_Float16)tile[hr][4 * c4 + 0];
            v.y = (_Float16)tile[hr][4 * c4 + 1];
            v.z = (_Float16)tile[hr][4 * c4 + 2];
            v.w = (_Float16)tile[hr][4 * c4 + 3];
            *(h4*)&xo[hr * 64 + 4 * c4] = v;        // 8B store, coalesced
        }
    } else {
        const int tid = (blockIdx.x - 1024) * 256 + threadIdx.x;  // 0..36863
        if (tid < COUT_ * KK_) {
            const int k   = tid % KK_;              // tap*64 + c
            const int o   = tid / KK_;
            const int c   = k & 63;
            const int tap = k >> 6;
            wA3[tid] = (_Float16)w[o * (C_ * K_) + c * K_ + tap];
        }
    }
}

// ---------------------------------------------------------------------------
// Fused im2col+GEMM. Block = 256 thr / 4 waves, 64 px x 64 cout; each wave
// independently handles 16 px x 64 cout. Gather identity: lane (g=lane>>3
// pixel-in-8, l8=lane&7 channel-octet); per dwordx4 instr the wave covers
// 8 px x 128B contiguous. Lane owns pixels (g, g+8). FINISH: packed fp16
// bilinear (v_pk_fma_f16) -> wave-private Bt. MFMA: 2 kc x 4 mh of
// 16x16x32_f16, B-tile = the wave's own 16 px. NO barrier in the loop.
// ---------------------------------------------------------------------------
__global__ __launch_bounds__(256, 4) void dcn_fused(
    const _Float16* __restrict__ xh,   // (N, HW, C) fp16
    const float* __restrict__ offset,  // (N, 2*K, H, W)
    const float* __restrict__ mask,    // (N, K, H, W)
    const _Float16* __restrict__ wA3,  // (COUT, KK) fp16, k = tap*64+c
    const float* __restrict__ bias,
    float* __restrict__ out)           // (N, Cout, H, W)
{
    const int tid  = threadIdx.x;
    const int lane = tid & 63;
    const int wv   = tid >> 6;
    const int quad = lane >> 4;        // MFMA: k-octet selector
    const int l16  = lane & 15;        // MFMA: row/col lane
    const int g    = lane >> 3;        // gather: pixel-in-8
    const int l8   = lane & 7;         // gather: channel octet

    const int lb  = (blockIdx.x & 7) * 128 + (blockIdx.x >> 3);  // XCD swizzle
    const int pxb = lb * 64;                     // 64 | HW_: one image per block
    const int n   = pxb >> 14;
    const int hwb = pxb & (HW_ - 1);
    const int hww = hwb + wv * 16;               // wave's hw base

    __shared__ h4  cwh[4][144];                  // 4.6 KB  [wv][p*9+t]
    __shared__ v4i ci[4][144];                   // 9.2 KB  [wv][p*9+t]
    __shared__ _Float16 Bt[4][2][16][72];        // 18.4 KB [wv][buf][px][c pad]

    // ---- wave-local coef phase: this wave's 16 px x 9 taps = 144 entries ----
#pragma unroll
    for (int r = 0; r < 3; ++r) {
        const int e = r * 64 + lane;
        if (e < 144) {
            const int p  = e / 9;                // magic-mul
            const int t  = e - p * 9;
            const int hw = hww + p;
            const int ho = hw >> 7;
            const int wo = hw & (W_ - 1);
            const int ky = t / KW_;
            const int kx = t - ky * KW_;

            const float offy = offset[n * (2 * K_ * HW_) + (2 * t + 0) * HW_ + hw];
            const float offx = offset[n * (2 * K_ * HW_) + (2 * t + 1) * HW_ + hw];
            const float mval = mask[n * (K_ * HW_) + t * HW_ + hw];

            const float py = (float)(ho - 1 + ky) + offy;   // stride=1,pad=1,dil=1
            const float qx = (float)(wo - 1 + kx) + offx;
            const float y0f = floorf(py), x0f = floorf(qx);
            const float ly = py - y0f, lx = qx - x0f;
            const int y0 = (int)y0f, x0 = (int)x0f;
            const int y1 = y0 + 1,   x1 = x0 + 1;
            const bool vy0 = (y0 >= 0) & (y0 < H_);
            const bool vy1 = (y1 >= 0) & (y1 < H_);
            const bool vx0 = (x0 >= 0) & (x0 < W_);
            const bool vx1 = (x1 >= 0) & (x1 < W_);
            const int cy0 = min(max(y0, 0), H_ - 1);
            const int cy1 = min(max(y1, 0), H_ - 1);
            const int cx0 = min(max(x0, 0), W_ - 1);
            const int cx1 = min(max(x1, 0), W_ - 1);

            h4 q;
            q.x = (_Float16)((1.f - ly) * (1.f - lx) * mval * ((vy0 && vx0) ? 1.f : 0.f));
            q.y = (_Float16)((1.f - ly) * lx         * mval * ((vy0 && vx1) ? 1.f : 0.f));
            q.z = (_Float16)(ly         * (1.f - lx) * mval * ((vy1 && vx0) ? 1.f : 0.f));
            q.w = (_Float16)(ly         * lx         * mval * ((vy1 && vx1) ? 1.f : 0.f));
            cwh[wv][e] = q;
            v4i ii;
            ii.x = cy0 * W_ + cx0;
            ii.y = cy0 * W_ + cx1;
            ii.z = cy1 * W_ + cx0;
            ii.w = cy1 * W_ + cx1;
            ci[wv][e] = ii;
        }
    }
    __syncthreads();                             // the ONLY barrier

    // gather base: this lane's channel octet (16B), fp16 units
    const _Float16* xb8 = xh + ((size_t)n * HW_) * 64 + 8 * l8;
    const int pa = g;                            // lane's pixel A (local 0..7)
    const int pb = g + 8;                        // lane's pixel B (local 8..15)

    v4f acc[4];                                  // mh: cout block mh*16
#pragma unroll
    for (int mh = 0; mh < 4; ++mh) acc[mh] = (v4f){0.f, 0.f, 0.f, 0.f};

    // register stages: [pixel A/B][corner 0..3], h8 each = 32 VGPR/stage
    h8 LA[2][4], LB[2][4];

    // issue tap t's 8 corner loads into stage R
#define ISSUE(t, R)                                                         \
    {                                                                       \
        const v4i oa = ci[wv][pa * 9 + (t)];                                \
        const v4i ob = ci[wv][pb * 9 + (t)];                                \
        R[0][0] = *(const h8*)(xb8 + (size_t)oa.x * 64);                    \
        R[0][1] = *(const h8*)(xb8 + (size_t)oa.y * 64);                    \
        R[0][2] = *(const h8*)(xb8 + (size_t)oa.z * 64);                    \
        R[0][3] = *(const h8*)(xb8 + (size_t)oa.w * 64);                    \
        R[1][0] = *(const h8*)(xb8 + (size_t)ob.x * 64);                    \
        R[1][1] = *(const h8*)(xb8 + (size_t)ob.y * 64);                    \
        R[1][2] = *(const h8*)(xb8 + (size_t)ob.z * 64);                    \
        R[1][3] = *(const h8*)(xb8 + (size_t)ob.w * 64);                    \
    }

    // consume stage R for tap t: packed-fp16 bilinear + wave-private LDS write
#define FINISH(t, R, b)                                                     \
    {                                                                       \
        _Pragma("unroll")                                                   \
        for (int h = 0; h < 2; ++h) {                                       \
            const int p = h * 8 + g;                                        \
            const h4 f = cwh[wv][p * 9 + (t)];                              \
            const h8 F0 = {f.x, f.x, f.x, f.x, f.x, f.x, f.x, f.x};         \
            const h8 F1 = {f.y, f.y, f.y, f.y, f.y, f.y, f.y, f.y};         \
            const h8 F2 = {f.z, f.z, f.z, f.z, f.z, f.z, f.z, f.z};         \
            const h8 F3 = {f.w, f.w, f.w, f.w, f.w, f.w, f.w, f.w};         \
            h8 rr = F0 * R[h][0];                                           \
            rr = __builtin_elementwise_fma(F1, R[h][1], rr);                \
            rr = __builtin_elementwise_fma(F2, R[h][2], rr);                \
            rr = __builtin_elementwise_fma(F3, R[h][3], rr);                \
            *(h8*)&Bt[wv][b][p][8 * l8] = rr;                               \
        }                                                                   \
    }

    // ---- prologue: fill the 2-deep pipeline ----
    ISSUE(0, LA)
    ISSUE(1, LB)
    FINISH(0, LA, 0)

    // ---- main loop: 9 taps, NO barriers, loads 2 taps ahead ----
#pragma unroll
    for (int t = 0; t < K_; ++t) {
        const int buf = t & 1;
        if ((t & 1) == 0) {
            if (t + 2 < K_) ISSUE(t + 2, LA)
        } else {
            if (t + 2 < K_) ISSUE(t + 2, LB)
        }

        // MFMA(t): B from wave's own Bt[buf], A from wA3 (L1-hot)
#pragma unroll
        for (int kc = 0; kc < 2; ++kc) {
            const h8 bfr = *(const h8*)&Bt[wv][buf][l16][kc * 32 + quad * 8];
#pragma unroll
            for (int mh = 0; mh < 4; ++mh) {
                const h8 afr = *(const h8*)(wA3 + (size_t)(mh * 16 + l16) * KK_
                                            + t * 64 + kc * 32 + quad * 8);
                acc[mh] = __builtin_amdgcn_mfma_f32_16x16x32_f16(
                    afr, bfr, acc[mh], 0, 0, 0);
            }
        }

        if ((t & 1) == 0) {
            if (t + 1 < K_) FINISH(t + 1, LB, buf ^ 1)
        } else {
            if (t + 1 < K_) FINISH(t + 1, LA, buf ^ 1)
        }
    }
#undef ISSUE
#undef FINISH

    // D layout (R4-verified, dtype-independent): col = l16 (px), row = quad*4+r
    float* outb = out + n * (COUT_ * HW_) + hwb + wv * 16 + l16;
#pragma unroll
    for (int mh = 0; mh < 4; ++mh)
#pragma unroll
        for (int r = 0; r < 4; ++r) {
            const int m = mh * 16 + quad * 4 + r;
            outb[m * HW_] = acc[mh][r] + bias[m];
        }
}

// ---------------------------------------------------------------------------
// Fallback (ws too small): R3-style direct fp32 kernel, no ws needed.
// ---------------------------------------------------------------------------
__global__ __launch_bounds__(256) void dcn_fallback(
    const float* __restrict__ x, const float* __restrict__ offset,
    const float* __restrict__ mask, const float* __restrict__ wptr,
    const float* __restrict__ bias, float* __restrict__ out)
{
    const int pix = blockIdx.x * 256 + threadIdx.x;
    const int n = pix >> 14, hw = pix & (HW_ - 1);
    const int ho = hw >> 7,  wo = hw & (W_ - 1);
    float acc[COUT_];
#pragma unroll
    for (int o = 0; o < COUT_; ++o) acc[o] = bias[o];
    const float* xn   = x + n * (C_ * HW_);
    const float* offn = offset + n * (2 * K_ * HW_) + hw;
    const float* mn   = mask + n * (K_ * HW_) + hw;
    for (int ct = 0; ct < C_; ct += 8) {
        for (int k = 0; k < K_; ++k) {
            const int ky = k / KW_, kx = k - ky * KW_;
            const float off_y = offn[(2 * k + 0) * HW_];
            const float off_x = offn[(2 * k + 1) * HW_];
            const float m = mn[k * HW_];
            const float py = (float)(ho - 1 + ky) + off_y;
            const float px = (float)(wo - 1 + kx) + off_x;
            const float y0f = floorf(py), x0f = floorf(px);
            const float ly = py - y0f, lx = px - x0f;
            const int y0 = (int)y0f, x0 = (int)x0f, y1 = y0 + 1, x1 = x0 + 1;
            const bool vy0 = (y0 >= 0) & (y0 < H_), vy1 = (y1 >= 0) & (y1 < H_);
            const bool vx0 = (x0 >= 0) & (x0 < W_), vx1 = (x1 >= 0) & (x1 < W_);
            const int cy0 = min(max(y0, 0), H_ - 1), cy1 = min(max(y1, 0), H_ - 1);
            const int cx0 = min(max(x0, 0), W_ - 1), cx1 = min(max(x1, 0), W_ - 1);
            const int i00 = cy0 * W_ + cx0, i01 = cy0 * W_ + cx1;
            const int i10 = cy1 * W_ + cx0, i11 = cy1 * W_ + cx1;
            const float f00 = (1.f - ly) * (1.f - lx) * m * ((vy0 && vx0) ? 1.f : 0.f);
            const float f01 = (1.f - ly) * lx * m * ((vy0 && vx1) ? 1.f : 0.f);
            const float f10 = ly * (1.f - lx) * m * ((vy1 && vx0) ? 1.f : 0.f);
            const float f11 = ly * lx * m * ((vy1 && vx1) ? 1.f : 0.f);
            for (int cc = 0; cc < 8; ++cc) {
                const int c = ct + cc;
                const float* xc = xn + c * HW_;
                const float val = fmaf(f00, xc[i00], fmaf(f01, xc[i01],
                                  fmaf(f10, xc[i10], f11 * xc[i11])));
#pragma unroll
                for (int o = 0; o < COUT_; ++o)
                    acc[o] = fmaf(wptr[o * (C_ * K_) + c * K_ + k], val, acc[o]);
            }
        }
    }
    float* outp = out + n * (COUT_ * HW_) + hw;
#pragma unroll
    for (int o = 0; o < COUT_; ++o) outp[o * HW_] = acc[o];
}

extern "C" void kernel_launch(void* const* d_in, const int* in_sizes, int n_in,
                              void* d_out, int out_size, void* d_ws, size_t ws_size,
                              hipStream_t stream) {
    const float* x      = (const float*)d_in[0];
    const float* offset = (const float*)d_in[1];
    const float* mask   = (const float*)d_in[2];
    const float* weight = (const float*)d_in[3];
    const float* bias   = (const float*)d_in[4];
    float* out = (float*)d_out;

    const size_t xh_bytes = (size_t)NPIX * C_ * sizeof(_Float16);  // 8.4 MB
    const size_t wA_bytes = (size_t)COUT_ * KK_ * sizeof(_Float16);// 73.7 KB

    if (ws_size >= xh_bytes + wA_bytes) {
        _Float16* xh  = (_Float16*)d_ws;
        _Float16* wA3 = (_Float16*)((char*)d_ws + xh_bytes);
        prep<<<1024 + 144, 256, 0, stream>>>(x, xh, weight, wA3);
        dcn_fused<<<NPIX / 64, 256, 0, stream>>>(xh, offset, mask, wA3, bias, out);
    } else {
        dcn_fallback<<<NPIX / 256, 256, 0, stream>>>(x, offset, mask, weight, bias, out);
    }
}